// Round 10
// baseline (364.404 us; speedup 1.0000x reference)
//
#include <hip/hip_runtime.h>
#include <stdint.h>

typedef unsigned short u16;
typedef unsigned int u32;
typedef __bf16 b16x8 __attribute__((ext_vector_type(8)));
typedef float f32x4 __attribute__((ext_vector_type(4)));

#define B_ 8
#define S_ 1024
#define H_ 16
#define HD_ 64
#define D_ 1024
#define M_ 8192

__device__ __forceinline__ u16 f2bf(float f) {
  u32 u = __float_as_uint(f);
  return (u16)((u + 0x7fffu + ((u >> 16) & 1u)) >> 16);
}
__device__ __forceinline__ u16 bfbits(float f) {
  union {
    __bf16 b;
    u16 u;
  } c;
  c.b = (__bf16)f;  // native V_CVT (RNE)
  return c.u;
}

__device__ __forceinline__ f32x4 mfma16(b16x8 a, b16x8 b, f32x4 c) {
  return __builtin_amdgcn_mfma_f32_16x16x32_bf16(a, b, c, 0, 0, 0);
}

// async global->LDS, 16B per lane. LDS dest = wave-uniform base + lane*16.
__device__ __forceinline__ void cp16(const u16* g, u16* l) {
  __builtin_amdgcn_global_load_lds(
      (const __attribute__((address_space(1))) u32*)(g),
      (__attribute__((address_space(3))) u32*)(l), 16, 0, 0);
}

// ---------------------------------------------------------------------------
// Weight convert+transpose: WT[n][k] = bf16(W[k][n]), W f32 1024x1024.
// wtq/wtk/wtv land contiguous in ws -> fused B matrix [3072][1024] for QKV.
// ---------------------------------------------------------------------------
__global__ __launch_bounds__(1024) void wconv_kernel(
    const float* __restrict__ w0, const float* __restrict__ w1,
    const float* __restrict__ w2, const float* __restrict__ w3,
    u16* __restrict__ t0, u16* __restrict__ t1, u16* __restrict__ t2,
    u16* __restrict__ t3) {
  __shared__ float tile[32][33];
  const int z = blockIdx.z;
  const float* src = (z == 0) ? w0 : (z == 1) ? w1 : (z == 2) ? w2 : w3;
  u16* dst = (z == 0) ? t0 : (z == 1) ? t1 : (z == 2) ? t2 : t3;
  const int tx = threadIdx.x, ty = threadIdx.y;
  const int x0 = blockIdx.x * 32, y0 = blockIdx.y * 32;
  tile[ty][tx] = src[(size_t)(y0 + ty) * D_ + x0 + tx];
  __syncthreads();
  dst[(size_t)(x0 + ty) * D_ + y0 + tx] = f2bf(tile[tx][ty]);
}

// ---------------------------------------------------------------------------
// x convert: f32 -> bf16, 8M elements, 4/thread
// ---------------------------------------------------------------------------
__global__ __launch_bounds__(256) void xconv_kernel(const float* __restrict__ x,
                                                    u16* __restrict__ xb) {
  const size_t i = ((size_t)blockIdx.x * 256 + threadIdx.x) * 4;
  const float4 v = *(const float4*)(x + i);
  u16 o[4] = {f2bf(v.x), f2bf(v.y), f2bf(v.z), f2bf(v.w)};
  uint2 pack;
  pack.x = ((u32)o[1] << 16) | o[0];
  pack.y = ((u32)o[3] << 16) | o[2];
  *(uint2*)(xb + i) = pack;
}

// ---------------------------------------------------------------------------
// QKV: 256x256 8-phase GEMM (m201-style). 512 threads = 8 waves (2M x 4N),
// wave tile 128x64, BK=64, 2 K-tiles/iter. LDS 128KB: buf0=even KT, buf1=odd.
// Rationale (round-9 counters): the 256x128 structure is LDS-pipe-bound
// (160KB reads/K-tile ~1900cy > MFMA 1240cy). Wave 128x64 cuts per-FLOP LDS
// bytes 1.67x -> MFMA-bound. 4 phases/K-tile, 16 MFMA each (quadrant nh,kk).
// Stage schedule (4 cp16 each): p1:B(odd) p4:A(even+2) p5:B(even+2)
// p8:A(odd+2); every stage >=3 phases before its read (covers HBM ~900cy).
// vmcnt(4) at p1/p5 only (never 0 mid-loop; last iter p5 = vmcnt(0)).
// Write-after-read: region staged only in the phase AFTER its last read
// phase; per-phase lgkmcnt(0)+barrier makes "read complete" block-wide.
// sched_barrier(0) fences contain per-phase live ranges (anti-spill: acc 128
// AGPR + af 32 + bf 8 VGPR must stay < 256; spill check = WRITE_SIZE).
// ---------------------------------------------------------------------------
__global__ __launch_bounds__(512, 2) void qkv_gemm_kernel(
    const u16* __restrict__ xb, const u16* __restrict__ wt3,
    const float* __restrict__ bq, const float* __restrict__ bk,
    const float* __restrict__ bv, u16* __restrict__ Q, u16* __restrict__ Kb,
    u16* __restrict__ VT) {
  __shared__ __align__(16) u16 lds[65536];  // 128 KB
  const int wg = blockIdx.x;
  const int xcd = wg & 7;
  const int s = wg >> 3;             // 0..47
  const int by = xcd * 4 + (s & 3);  // 0..31: A panels pinned per XCD
  const int bx = s >> 2;             // 0..11
  const int m0 = by * 256;
  const int n0 = bx * 256;  // fused col base 0..2816

  const int t = threadIdx.x;
  const int lane = t & 63, w = t >> 6;
  const int l15 = lane & 15, q4 = lane >> 4;
  const int wm = w >> 2, wn = w & 3;

  const int rbase = t >> 3;                      // 0..63
  const int scol = ((t & 7) ^ (rbase & 7)) * 8;  // pre-swizzled global col
  const u16* Ag = xb + (size_t)(m0 + rbase) * D_ + scol;
  const u16* Bg = wt3 + (size_t)(n0 + rbase) * D_ + scol;

  // stage one operand tile (256x64 = 32KB = 4 cp16/thread) into buf(kt&1)
  auto STAGE_A = [&](int kt) {
    u16* dst = lds + (kt & 1) * 32768;
    const int k0 = kt * 64;
#pragma unroll
    for (int c = 0; c < 4; ++c)
      cp16(Ag + (size_t)(c * 64) * D_ + k0, dst + c * 4096 + t * 8);
  };
  auto STAGE_B = [&](int kt) {
    u16* dst = lds + (kt & 1) * 32768 + 16384;
    const int k0 = kt * 64;
#pragma unroll
    for (int c = 0; c < 4; ++c)
      cp16(Bg + (size_t)(c * 64) * D_ + k0, dst + c * 4096 + t * 8);
  };

  const f32x4 zero = {0.f, 0.f, 0.f, 0.f};
  f32x4 acc[8][4];
#pragma unroll
  for (int mf = 0; mf < 8; ++mf)
#pragma unroll
    for (int nc = 0; nc < 4; ++nc) acc[mf][nc] = zero;

  const int sx = l15 & 7;
  const int abase = wm * 8192 + l15 * 64;           // A row (wm*128+mf*16+l15)
  const int bbase = 16384 + wn * 4096 + l15 * 64;   // B^T row (wn*64+..+l15)
  const int cc0 = (q4 ^ sx) * 8;                    // kk0 chunk
  const int cc1 = ((4 + q4) ^ sx) * 8;              // kk1 chunk

  // prologue: A(0), B(0), A(1) = 12 cp16 -> p1's vmcnt(4) retires A0,B0
  STAGE_A(0);
  STAGE_B(0);
  STAGE_A(1);

#pragma unroll 1
  for (int i = 0; i < 8; ++i) {
    const int kt0 = 2 * i, kt1 = 2 * i + 1;
    const u16* be_ = lds;          // even-KT buffer
    const u16* bo_ = lds + 32768;  // odd-KT buffer
    const bool pf = (i < 7);
    b16x8 af[8], bfa, bfb;

    // ---- p1: even kk0 nh0; stage B(kt1) ----
    asm volatile("s_waitcnt vmcnt(4)" ::: "memory");
    asm volatile("s_barrier" ::: "memory");
#pragma unroll
    for (int mf = 0; mf < 8; ++mf)
      af[mf] = *(const b16x8*)(be_ + abase + mf * 1024 + cc0);
    bfa = *(const b16x8*)(be_ + bbase + cc0);
    bfb = *(const b16x8*)(be_ + bbase + 1024 + cc0);
    STAGE_B(kt1);
    asm volatile("s_barrier" ::: "memory");
    asm volatile("s_waitcnt lgkmcnt(0)" ::: "memory");
    __builtin_amdgcn_sched_barrier(0);
    __builtin_amdgcn_s_setprio(1);
#pragma unroll
    for (int mf = 0; mf < 8; ++mf) {
      acc[mf][0] = mfma16(af[mf], bfa, acc[mf][0]);
      acc[mf][1] = mfma16(af[mf], bfb, acc[mf][1]);
    }
    __builtin_amdgcn_s_setprio(0);
    asm volatile("s_barrier" ::: "memory");
    __builtin_amdgcn_sched_barrier(0);

    // ---- p2: even kk0 nh1 ----
    bfa = *(const b16x8*)(be_ + bbase + 2048 + cc0);
    bfb = *(const b16x8*)(be_ + bbase + 3072 + cc0);
    asm volatile("s_barrier" ::: "memory");
    asm volatile("s_waitcnt lgkmcnt(0)" ::: "memory");
    __builtin_amdgcn_sched_barrier(0);
    __builtin_amdgcn_s_setprio(1);
#pragma unroll
    for (int mf = 0; mf < 8; ++mf) {
      acc[mf][2] = mfma16(af[mf], bfa, acc[mf][2]);
      acc[mf][3] = mfma16(af[mf], bfb, acc[mf][3]);
    }
    __builtin_amdgcn_s_setprio(0);
    asm volatile("s_barrier" ::: "memory");
    __builtin_amdgcn_sched_barrier(0);

    // ---- p3: even kk1 nh0 ----
#pragma unroll
    for (int mf = 0; mf < 8; ++mf)
      af[mf] = *(const b16x8*)(be_ + abase + mf * 1024 + cc1);
    bfa = *(const b16x8*)(be_ + bbase + cc1);
    bfb = *(const b16x8*)(be_ + bbase + 1024 + cc1);
    asm volatile("s_barrier" ::: "memory");
    asm volatile("s_waitcnt lgkmcnt(0)" ::: "memory");
    __builtin_amdgcn_sched_barrier(0);
    __builtin_amdgcn_s_setprio(1);
#pragma unroll
    for (int mf = 0; mf < 8; ++mf) {
      acc[mf][0] = mfma16(af[mf], bfa, acc[mf][0]);
      acc[mf][1] = mfma16(af[mf], bfb, acc[mf][1]);
    }
    __builtin_amdgcn_s_setprio(0);
    asm volatile("s_barrier" ::: "memory");
    __builtin_amdgcn_sched_barrier(0);

    // ---- p4: even kk1 nh1; stage A(kt0+2) (A(even) reads done at p3) ----
    bfa = *(const b16x8*)(be_ + bbase + 2048 + cc1);
    bfb = *(const b16x8*)(be_ + bbase + 3072 + cc1);
    if (pf) STAGE_A(kt0 + 2);
    asm volatile("s_barrier" ::: "memory");
    asm volatile("s_waitcnt lgkmcnt(0)" ::: "memory");
    __builtin_amdgcn_sched_barrier(0);
    __builtin_amdgcn_s_setprio(1);
#pragma unroll
    for (int mf = 0; mf < 8; ++mf) {
      acc[mf][2] = mfma16(af[mf], bfa, acc[mf][2]);
      acc[mf][3] = mfma16(af[mf], bfb, acc[mf][3]);
    }
    __builtin_amdgcn_s_setprio(0);
    asm volatile("s_barrier" ::: "memory");
    __builtin_amdgcn_sched_barrier(0);

    // ---- p5: odd kk0 nh0; stage B(kt0+2) (B(even) reads done at p4) ----
    if (pf)
      asm volatile("s_waitcnt vmcnt(4)" ::: "memory");
    else
      asm volatile("s_waitcnt vmcnt(0)" ::: "memory");
    asm volatile("s_barrier" ::: "memory");
#pragma unroll
    for (int mf = 0; mf < 8; ++mf)
      af[mf] = *(const b16x8*)(bo_ + abase + mf * 1024 + cc0);
    bfa = *(const b16x8*)(bo_ + bbase + cc0);
    bfb = *(const b16x8*)(bo_ + bbase + 1024 + cc0);
    if (pf) STAGE_B(kt0 + 2);
    asm volatile("s_barrier" ::: "memory");
    asm volatile("s_waitcnt lgkmcnt(0)" ::: "memory");
    __builtin_amdgcn_sched_barrier(0);
    __builtin_amdgcn_s_setprio(1);
#pragma unroll
    for (int mf = 0; mf < 8; ++mf) {
      acc[mf][0] = mfma16(af[mf], bfa, acc[mf][0]);
      acc[mf][1] = mfma16(af[mf], bfb, acc[mf][1]);
    }
    __builtin_amdgcn_s_setprio(0);
    asm volatile("s_barrier" ::: "memory");
    __builtin_amdgcn_sched_barrier(0);

    // ---- p6: odd kk0 nh1 ----
    bfa = *(const b16x8*)(bo_ + bbase + 2048 + cc0);
    bfb = *(const b16x8*)(bo_ + bbase + 3072 + cc0);
    asm volatile("s_barrier" ::: "memory");
    asm volatile("s_waitcnt lgkmcnt(0)" ::: "memory");
    __builtin_amdgcn_sched_barrier(0);
    __builtin_amdgcn_s_setprio(1);
#pragma unroll
    for (int mf = 0; mf < 8; ++mf) {
      acc[mf][2] = mfma16(af[mf], bfa, acc[mf][2]);
      acc[mf][3] = mfma16(af[mf], bfb, acc[mf][3]);
    }
    __builtin_amdgcn_s_setprio(0);
    asm volatile("s_barrier" ::: "memory");
    __builtin_amdgcn_sched_barrier(0);

    // ---- p7: odd kk1 nh0 ----
#pragma unroll
    for (int mf = 0; mf < 8; ++mf)
      af[mf] = *(const b16x8*)(bo_ + abase + mf * 1024 + cc1);
    bfa = *(const b16x8*)(bo_ + bbase + cc1);
    bfb = *(const b16x8*)(bo_ + bbase + 1024 + cc1);
    asm volatile("s_barrier" ::: "memory");
    asm volatile("s_waitcnt lgkmcnt(0)" ::: "memory");
    __builtin_amdgcn_sched_barrier(0);
    __builtin_amdgcn_s_setprio(1);
#pragma unroll
    for (int mf = 0; mf < 8; ++mf) {
      acc[mf][0] = mfma16(af[mf], bfa, acc[mf][0]);
      acc[mf][1] = mfma16(af[mf], bfb, acc[mf][1]);
    }
    __builtin_amdgcn_s_setprio(0);
    asm volatile("s_barrier" ::: "memory");
    __builtin_amdgcn_sched_barrier(0);

    // ---- p8: odd kk1 nh1; stage A(kt1+2) (A(odd) reads done at p7) ----
    bfa = *(const b16x8*)(bo_ + bbase + 2048 + cc1);
    bfb = *(const b16x8*)(bo_ + bbase + 3072 + cc1);
    if (pf) STAGE_A(kt1 + 2);
    asm volatile("s_barrier" ::: "memory");
    asm volatile("s_waitcnt lgkmcnt(0)" ::: "memory");
    __builtin_amdgcn_sched_barrier(0);
    __builtin_amdgcn_s_setprio(1);
#pragma unroll
    for (int mf = 0; mf < 8; ++mf) {
      acc[mf][2] = mfma16(af[mf], bfa, acc[mf][2]);
      acc[mf][3] = mfma16(af[mf], bfb, acc[mf][3]);
    }
    __builtin_amdgcn_s_setprio(0);
    asm volatile("s_barrier" ::: "memory");
    __builtin_amdgcn_sched_barrier(0);
  }

  // epilogue (verified in round-4's 256^2 run): z uniform per block
  const int z = n0 >> 10;
  u16* out = (z == 0) ? Q : (z == 1) ? Kb : VT;
  const float* bias = (z == 0) ? bq : (z == 1) ? bk : bv;

  for (int nt = 0; nt < 4; ++nt) {
    const int nf = n0 + wn * 64 + nt * 16 + l15;  // fused col
    const int n1 = nf & 1023;                     // col within matrix
    const float bias_v = bias[n1];
    const int h = n1 >> 6, hd = n1 & 63;
    for (int mt = 0; mt < 8; ++mt) {
      for (int r = 0; r < 4; ++r) {
        const int m = m0 + wm * 128 + mt * 16 + q4 * 4 + r;
        const int b = m >> 10, ss = m & 1023;
        const float v = acc[mt][nt][r] + bias_v;
        size_t idx;
        if (z < 2)
          idx = (((size_t)(b * H_ + h)) * S_ + ss) * HD_ + hd;
        else
          idx = (((size_t)(b * H_ + h)) * HD_ + hd) * S_ + ss;
        out[idx] = f2bf(v);
      }
    }
  }
}

// ---------------------------------------------------------------------------
// 256x128 GEMM mainloop (verified round-5/9) -- used by out_gemm (grid 256
// = 1 full round; BN=256 would halve its grid).
// ---------------------------------------------------------------------------
#define ABUF_ 16384  // u16: 256x64 A tile
#define BBUF_ 8192   // u16: 128x64 B tile
#define BUFSZ_ (ABUF_ + BBUF_)

__device__ __forceinline__ void gemm256x128_mainloop(
    const u16* __restrict__ A, const u16* __restrict__ BT, int K, int m0,
    int n0, u16* lds, f32x4 (&acc)[8][2]) {
  const int t = threadIdx.x;
  const int lane = t & 63;
  const int l15 = lane & 15;
  const int q4 = lane >> 4;
  const int w = t >> 6;
  const int wm = w >> 2;  // 0..1 -> 128-row half
  const int wn = w & 3;   // 0..3 -> 32-col slice

  const f32x4 zero = {0.f, 0.f, 0.f, 0.f};
#pragma unroll
  for (int mt = 0; mt < 8; ++mt)
#pragma unroll
    for (int nt = 0; nt < 2; ++nt) acc[mt][nt] = zero;

  const int rbase = t >> 3;                      // 0..63
  const int scol = ((t & 7) ^ (rbase & 7)) * 8;  // pre-swizzled global col
  const u16* Ag = A + (size_t)(m0 + rbase) * K + scol;
  const u16* Bg = BT + (size_t)(n0 + rbase) * K + scol;
  const int sx = l15 & 7;

  auto STAGE = [&](int kt, int bufi) {
    u16* Ab = lds + bufi * BUFSZ_;
    u16* Bb = Ab + ABUF_;
    const int k0 = kt * 64;
#pragma unroll
    for (int c = 0; c < 4; ++c)
      cp16(Ag + (size_t)(c * 64) * K + k0, Ab + c * 4096 + t * 8);
#pragma unroll
    for (int c = 0; c < 2; ++c)
      cp16(Bg + (size_t)(c * 64) * K + k0, Bb + c * 4096 + t * 8);
  };

  const int NT = K / 64;  // 16
  STAGE(0, 0);
  STAGE(1, 1);

  int cur = 0;
  for (int kt = 0; kt < NT; ++kt) {
    if (kt + 2 < NT) {
      int nb = cur + 2;
      if (nb >= 3) nb -= 3;
      STAGE(kt + 2, nb);
    }
    if (kt + 2 < NT)
      asm volatile("s_waitcnt vmcnt(12)" ::: "memory");
    else if (kt + 1 < NT)
      asm volatile("s_waitcnt vmcnt(6)" ::: "memory");
    else
      asm volatile("s_waitcnt vmcnt(0)" ::: "memory");
    asm volatile("s_barrier" ::: "memory");

    const u16* Ab = lds + cur * BUFSZ_;
    const u16* Bb = Ab + ABUF_;

    b16x8 af[8][2], bf2[2][2];
#pragma unroll
    for (int kk = 0; kk < 2; ++kk) {
      const int cc = ((kk * 4 + q4) ^ sx) * 8;
#pragma unroll
      for (int mt = 0; mt < 8; ++mt)
        af[mt][kk] = *(const b16x8*)(Ab + (wm * 128 + mt * 16 + l15) * 64 + cc);
#pragma unroll
      for (int nt = 0; nt < 2; ++nt)
        bf2[nt][kk] = *(const b16x8*)(Bb + (wn * 32 + nt * 16 + l15) * 64 + cc);
    }
    __builtin_amdgcn_sched_barrier(0);

    __builtin_amdgcn_s_setprio(1);
#pragma unroll
    for (int mt = 0; mt < 8; ++mt) {
      acc[mt][0] = mfma16(af[mt][0], bf2[0][0], acc[mt][0]);
      acc[mt][1] = mfma16(af[mt][0], bf2[1][0], acc[mt][1]);
    }
    __builtin_amdgcn_s_setprio(0);

    asm volatile("s_waitcnt lgkmcnt(0)" ::: "memory");
    asm volatile("s_barrier" ::: "memory");

    __builtin_amdgcn_s_setprio(1);
#pragma unroll
    for (int mt = 0; mt < 8; ++mt) {
      acc[mt][0] = mfma16(af[mt][1], bf2[0][1], acc[mt][0]);
      acc[mt][1] = mfma16(af[mt][1], bf2[1][1], acc[mt][1]);
    }
    __builtin_amdgcn_s_setprio(0);

    ++cur;
    if (cur == 3) cur = 0;
  }
}

// ---------------------------------------------------------------------------
// Flash attention, fixed-max softmax, transposed-score formulation.
// QBLK=128 (512 threads, 8 waves), verified round-6. Unchanged.
// ---------------------------------------------------------------------------
#define PAD_ 68   // K/V row stride (measured conflict-free)
#define QPAD_ 72  // Q/P row stride (144B = 16B-aligned for b128)
__global__ __launch_bounds__(512) void attn_kernel(
    const u16* __restrict__ Q, const u16* __restrict__ Kb,
    const u16* __restrict__ VT, const int* __restrict__ mask,
    u16* __restrict__ ctx) {
  __shared__ __align__(16) u16 QPlds[128 * QPAD_];  // Q tile, then P buffers
  __shared__ __align__(16) u16 Klds[64 * PAD_];
  __shared__ __align__(16) u16 Vlds[64 * PAD_];
  __shared__ __align__(16) float Mlds[1024];  // -14427 * mask[key]

  const int t = threadIdx.x;
  const int lane = t & 63, w = t >> 6;  // w 0..7
  const int l15 = lane & 15, q4 = lane >> 4;
  const int id = blockIdx.x;
  const int bh = id & 127;  // XCD = id%8 = bh%8 -> q-tiles of a bh co-locate
  const int b = bh >> 4, h = bh & 15;
  const int q0 = (id >> 7) * 128;  // 8 q-tiles of 128 rows

  const u16* Qbh = Q + (size_t)bh * S_ * HD_;
  const u16* Kbh = Kb + (size_t)bh * S_ * HD_;
  const u16* Vbh = VT + (size_t)bh * S_ * HD_;  // [HD][S]
  const int* maskb = mask + b * S_;

  const int srow = t >> 3, scol = (t & 7) * 8;  // srow 0..63
  {  // stage Q tile [128][64] + mask into LDS
    b16x8 q0v = *(const b16x8*)(Qbh + (size_t)(q0 + srow) * HD_ + scol);
    b16x8 q1v = *(const b16x8*)(Qbh + (size_t)(q0 + srow + 64) * HD_ + scol);
    const int2 mv = *(const int2*)(maskb + t * 2);
    *(b16x8*)(QPlds + srow * QPAD_ + scol) = q0v;
    *(b16x8*)(QPlds + (srow + 64) * QPAD_ + scol) = q1v;
    float2 mf;
    mf.x = -14427.0f * (float)mv.x;
    mf.y = -14427.0f * (float)mv.y;
    *(float2*)(Mlds + t * 2) = mf;
  }
  __syncthreads();
  // Q B-frags (lane holds Q[q=l15][d=q4*8+j]), wave-private rows
  b16x8 aq[2];
  aq[0] = *(const b16x8*)(QPlds + (w * 16 + l15) * QPAD_ + q4 * 8);
  aq[1] = *(const b16x8*)(QPlds + (w * 16 + l15) * QPAD_ + 32 + q4 * 8);

  const f32x4 zero = {0.f, 0.f, 0.f, 0.f};
  f32x4 acc[4];  // O^T tiles: acc[nt] row d=nt*16+q4*4+r, col q=l15
  for (int nt = 0; nt < 4; ++nt) acc[nt] = zero;
  float lsum = 0.f;                  // partial row-sum for q=l15
  u16* Pw = QPlds + w * 16 * QPAD_;  // wave-private P: [q(16)][key(64)]
  const float c1 = 0.18033688f;      // 0.125 * log2(e)

  // prologue: K/V registers for j=0 (one row each with 512 threads)
  b16x8 kv0 = *(const b16x8*)(Kbh + (size_t)srow * HD_ + scol);
  b16x8 vv0 = *(const b16x8*)(Vbh + (size_t)srow * S_ + scol);

  for (int j = 0; j < 16; ++j) {
    const int key0 = j * 64;
    __syncthreads();  // (A) prior iteration's K/V LDS reads complete
    *(b16x8*)(Klds + srow * PAD_ + scol) = kv0;
    *(b16x8*)(Vlds + srow * PAD_ + scol) = vv0;
    __syncthreads();  // (B) staging visible

    if (j < 15) {  // prefetch next tile's K/V during compute
      const int kn = key0 + 64;
      kv0 = *(const b16x8*)(Kbh + (size_t)(kn + srow) * HD_ + scol);
      vv0 = *(const b16x8*)(Vbh + (size_t)srow * S_ + kn + scol);
    }

    // S^T = K·Q^T: sf[nt] rows key=nt*16+q4*4+r, col q=l15
    f32x4 sf[4];
    for (int nt = 0; nt < 4; ++nt) sf[nt] = zero;
    for (int kk = 0; kk < 2; ++kk)
      for (int nt = 0; nt < 4; ++nt) {
        b16x8 bk =
            *(const b16x8*)(Klds + (nt * 16 + l15) * PAD_ + kk * 32 + q4 * 8);
        sf[nt] = mfma16(bk, aq[kk], sf[nt]);
      }

    // fixed-max softmax; mask indexed by key (row) -> broadcast float4
    for (int nt = 0; nt < 4; ++nt) {
      const float4 mk = *(const float4*)(Mlds + key0 + nt * 16 + q4 * 4);
      float p0 = __builtin_amdgcn_exp2f(sf[nt][0] * c1 + mk.x);
      float p1 = __builtin_amdgcn_exp2f(sf[nt][1] * c1 + mk.y);
      float p2 = __builtin_amdgcn_exp2f(sf[nt][2] * c1 + mk.z);
      float p3 = __builtin_amdgcn_exp2f(sf[nt][3] * c1 + mk.w);
      lsum += (p0 + p1) + (p2 + p3);
      uint2 pk;
      pk.x = ((u32)bfbits(p1) << 16) | bfbits(p0);
      pk.y = ((u32)bfbits(p3) << 16) | bfbits(p2);
      // P[q=l15][key=nt*16+q4*4 .. +3]: 4 consecutive keys, one b64 write
      *(uint2*)(Pw + l15 * QPAD_ + nt * 16 + q4 * 4) = pk;
    }
    // wave-private handoff: drain the 4 P writes only
    asm volatile("s_waitcnt lgkmcnt(0)" ::: "memory");

    // O^T += V^T·P: A=V-frag (same read as before), B=P-frag (b128 row read)
    for (int kk = 0; kk < 2; ++kk) {
      b16x8 bp = *(const b16x8*)(Pw + l15 * QPAD_ + kk * 32 + q4 * 8);
      for (int nt = 0; nt < 4; ++nt) {
        b16x8 vb =
            *(const b16x8*)(Vlds + (nt * 16 + l15) * PAD_ + kk * 32 + q4 * 8);
        acc[nt] = mfma16(vb, bp, acc[nt]);
      }
    }
  }

  // row-sum: quads hold disjoint key quarters -> reduce across quads
  lsum += __shfl_xor(lsum, 16);
  lsum += __shfl_xor(lsum, 32);
  const float inv = 1.0f / lsum;

  // epilogue: lane writes 4 consecutive d at fixed row s -> dwordx2 stores
  const int srw = q0 + w * 16 + l15;
  u16* crow = ctx + ((size_t)(b * S_ + srw)) * D_ + h * 64;
  for (int nt = 0; nt < 4; ++nt) {
    uint2 pk;
    pk.x = ((u32)bfbits(acc[nt][1] * inv) << 16) | bfbits(acc[nt][0] * inv);
    pk.y = ((u32)bfbits(acc[nt][3] * inv) << 16) | bfbits(acc[nt][2] * inv);
    *(uint2*)(crow + nt * 16 + q4 * 4) = pk;
  }
}

// ---------------------------------------------------------------------------
// Output projection + bias + residual(x f32) -> y (fp32).
// Grid 256 = 32by x 8bx = exactly 1 round at 1 block/CU. Same L2-residency
// swizzle: XCD x owns by {4x..4x+3} (A 2MB) + full wto (2MB) = 4MB.
// ---------------------------------------------------------------------------
__global__ __launch_bounds__(512, 2) void out_gemm_kernel(
    const u16* __restrict__ ctx, const u16* __restrict__ wto,
    const float* __restrict__ bo, const float* __restrict__ x,
    float* __restrict__ y) {
  __shared__ __align__(16) u16 lds[3 * BUFSZ_];  // 144 KB
  const int wg = blockIdx.x;
  const int xcd = wg & 7;
  const int s = wg >> 3;             // 0..31
  const int by = xcd * 4 + (s & 3);  // 0..31
  const int bx = s >> 2;             // 0..7
  const int m0 = by * 256, n0 = bx * 128;

  f32x4 acc[8][2];
  gemm256x128_mainloop(ctx, wto, D_, m0, n0, lds, acc);

  const int t = threadIdx.x;
  const int lane = t & 63, w = t >> 6;
  const int l15 = lane & 15, q4 = lane >> 4;
  const int wm = w >> 2, wn = w & 3;

  for (int nt = 0; nt < 2; ++nt) {
    const int n = n0 + wn * 32 + nt * 16 + l15;
    const float bias = bo[n];
    for (int mt = 0; mt < 8; ++mt) {
      for (int r = 0; r < 4; ++r) {
        const int m = m0 + wm * 128 + mt * 16 + q4 * 4 + r;
        y[(size_t)m * D_ + n] = acc[mt][nt][r] + bias + x[(size_t)m * D_ + n];
      }
    }
  }
}

// ---------------------------------------------------------------------------
// Row LayerNorm: one block per row of 1024, f32 in, f32 out
// ---------------------------------------------------------------------------
__global__ __launch_bounds__(256) void ln_kernel(const float* __restrict__ y,
                                                 const float* __restrict__ g,
                                                 const float* __restrict__ be,
                                                 float* __restrict__ out) {
  const int row = blockIdx.x, t = threadIdx.x;
  const float* yr = y + (size_t)row * D_;
  const float4 v = *(const float4*)(yr + t * 4);
  float s = v.x + v.y + v.z + v.w;
  float ss = v.x * v.x + v.y * v.y + v.z * v.z + v.w * v.w;
  for (int off = 1; off < 64; off <<= 1) {
    s += __shfl_xor(s, off);
    ss += __shfl_xor(ss, off);
  }
  __shared__ float red[8];
  const int w = t >> 6, lane = t & 63;
  if (lane == 0) {
    red[w] = s;
    red[4 + w] = ss;
  }
  __syncthreads();
  s = red[0] + red[1] + red[2] + red[3];
  ss = red[4] + red[5] + red[6] + red[7];
  const float mu = s * (1.f / 1024.f);
  const float var = ss * (1.f / 1024.f) - mu * mu;
  const float rs = rsqrtf(var + 1e-6f);
  const int c = t * 4;
  const float4 gv = *(const float4*)(g + c);
  const float4 bv = *(const float4*)(be + c);
  float4 o;
  o.x = (v.x - mu) * rs * gv.x + bv.x;
  o.y = (v.y - mu) * rs * gv.y + bv.y;
  o.z = (v.z - mu) * rs * gv.z + bv.z;
  o.w = (v.w - mu) * rs * gv.w + bv.w;
  *(float4*)(out + (size_t)row * D_ + c) = o;
}

// ---------------------------------------------------------------------------
extern "C" void kernel_launch(void* const* d_in, const int* in_sizes, int n_in,
                              void* d_out, int out_size, void* d_ws,
                              size_t ws_size, hipStream_t stream) {
  const float* x = (const float*)d_in[0];
  const int* mask = (const int*)d_in[1];
  const float* wq = (const float*)d_in[2];
  const float* bq = (const float*)d_in[3];
  const float* wk = (const float*)d_in[4];
  const float* bk = (const float*)d_in[5];
  const float* wv = (const float*)d_in[6];
  const float* bv = (const float*)d_in[7];
  const float* wo = (const float*)d_in[8];
  const float* bo = (const float*)d_in[9];
  const float* gamma = (const float*)d_in[10];
  const float* beta = (const float*)d_in[11];
  float* out = (float*)d_out;

  char* ws = (char*)d_ws;
  const size_t MB = 1024ull * 1024ull;
  u16* wtq = (u16*)(ws + 0 * MB);  // wtq/wtk/wtv contiguous = fused [3072][1024]
  u16* wtk = (u16*)(ws + 2 * MB);
  u16* wtv = (u16*)(ws + 4 * MB);
  u16* wto = (u16*)(ws + 6 * MB);
  u16* xb = (u16*)(ws + 8 * MB);    // 16MB bf16 x; dead after qkv_gemm
  u16* ctx = (u16*)(ws + 8 * MB);   // aliases xb (written by attn)
  u16* Qb = (u16*)(ws + 24 * MB);   // 16MB; dead after attn
  u16* Kb = (u16*)(ws + 40 * MB);   // 16MB; dead after attn
  u16* VTb = (u16*)(ws + 56 * MB);  // 16MB
  float* y = (float*)(ws + 24 * MB);  // 32MB fp32, aliases Qb+Kb
  // total: 72MB

  wconv_kernel<<<dim3(32, 32, 4), dim3(32, 32), 0, stream>>>(
      wq, wk, wv, wo, wtq, wtk, wtv, wto);
  xconv_kernel<<<8192, 256, 0, stream>>>(x, xb);
  qkv_gemm_kernel<<<384, 512, 0, stream>>>(xb, wtq, bq, bk, bv, Qb, Kb, VTb);
  attn_kernel<<<1024, 512, 0, stream>>>(Qb, Kb, VTb, mask, ctx);
  out_gemm_kernel<<<256, 512, 0, stream>>>(ctx, wto, bo, x, y);
  ln_kernel<<<8192, 256, 0, stream>>>(y, gamma, beta, out);
}

// Round 11
// 278.693 us; speedup vs baseline: 1.3075x; 1.3075x over previous
//
#include <hip/hip_runtime.h>
#include <stdint.h>

typedef unsigned short u16;
typedef unsigned int u32;
typedef __bf16 b16x8 __attribute__((ext_vector_type(8)));
typedef float f32x4 __attribute__((ext_vector_type(4)));

#define B_ 8
#define S_ 1024
#define H_ 16
#define HD_ 64
#define D_ 1024
#define M_ 8192

__device__ __forceinline__ u16 f2bf(float f) {
  u32 u = __float_as_uint(f);
  return (u16)((u + 0x7fffu + ((u >> 16) & 1u)) >> 16);
}
__device__ __forceinline__ u16 bfbits(float f) {
  union {
    __bf16 b;
    u16 u;
  } c;
  c.b = (__bf16)f;  // native V_CVT (RNE)
  return c.u;
}

__device__ __forceinline__ f32x4 mfma16(b16x8 a, b16x8 b, f32x4 c) {
  return __builtin_amdgcn_mfma_f32_16x16x32_bf16(a, b, c, 0, 0, 0);
}

// async global->LDS, 16B per lane. LDS dest = wave-uniform base + lane*16.
__device__ __forceinline__ void cp16(const u16* g, u16* l) {
  __builtin_amdgcn_global_load_lds(
      (const __attribute__((address_space(1))) u32*)(g),
      (__attribute__((address_space(3))) u32*)(l), 16, 0, 0);
}

// ---------------------------------------------------------------------------
// Weight convert+transpose: WT[n][k] = bf16(W[k][n]), W f32 1024x1024.
// wtq/wtk/wtv land contiguous in ws -> fused B matrix [3072][1024] for QKV.
// ---------------------------------------------------------------------------
__global__ __launch_bounds__(1024) void wconv_kernel(
    const float* __restrict__ w0, const float* __restrict__ w1,
    const float* __restrict__ w2, const float* __restrict__ w3,
    u16* __restrict__ t0, u16* __restrict__ t1, u16* __restrict__ t2,
    u16* __restrict__ t3) {
  __shared__ float tile[32][33];
  const int z = blockIdx.z;
  const float* src = (z == 0) ? w0 : (z == 1) ? w1 : (z == 2) ? w2 : w3;
  u16* dst = (z == 0) ? t0 : (z == 1) ? t1 : (z == 2) ? t2 : t3;
  const int tx = threadIdx.x, ty = threadIdx.y;
  const int x0 = blockIdx.x * 32, y0 = blockIdx.y * 32;
  tile[ty][tx] = src[(size_t)(y0 + ty) * D_ + x0 + tx];
  __syncthreads();
  dst[(size_t)(x0 + ty) * D_ + y0 + tx] = f2bf(tile[tx][ty]);
}

// ---------------------------------------------------------------------------
// x convert: f32 -> bf16, 8M elements, 4/thread
// ---------------------------------------------------------------------------
__global__ __launch_bounds__(256) void xconv_kernel(const float* __restrict__ x,
                                                    u16* __restrict__ xb) {
  const size_t i = ((size_t)blockIdx.x * 256 + threadIdx.x) * 4;
  const float4 v = *(const float4*)(x + i);
  u16 o[4] = {f2bf(v.x), f2bf(v.y), f2bf(v.z), f2bf(v.w)};
  uint2 pack;
  pack.x = ((u32)o[1] << 16) | o[0];
  pack.y = ((u32)o[3] << 16) | o[2];
  *(uint2*)(xb + i) = pack;
}

// ---------------------------------------------------------------------------
// 256x128 GEMM mainloop, BK=64, 512 threads, triple-buffered LDS (48KB/buf,
// 144KB) with counted-vmcnt pipeline (verified rounds 5-9; sync structure
// UNCHANGED).
// ROUND-11 CHANGE (single edit): wave re-tile 2Mx4N (128x32/wave) ->
// 4Mx2N (64x64/wave). Reads/K-tile/wave drop 20 -> 16 b128 (A 4x2 + B 4x2)
// for the same 32 MFMA -- LDS-read volume 160KB -> 128KB/K-tile, attacking
// the measured LDS-pipe term (3830cy/K-tile, MFMA only 1240). acc stays
// [4][4]=64 regs -- no spill risk (256^2 acc=128 spilled twice: r4, r10;
// 512-thread blocks cap at 256 unified regs/wave).
// ---------------------------------------------------------------------------
#define ABUF_ 16384  // u16: 256x64 A tile
#define BBUF_ 8192   // u16: 128x64 B tile
#define BUFSZ_ (ABUF_ + BBUF_)

__device__ __forceinline__ void gemm256x128_mainloop(
    const u16* __restrict__ A, const u16* __restrict__ BT, int K, int m0,
    int n0, u16* lds, f32x4 (&acc)[4][4]) {
  const int t = threadIdx.x;
  const int lane = t & 63;
  const int l15 = lane & 15;
  const int q4 = lane >> 4;
  const int w = t >> 6;
  const int wm = w >> 1;  // 0..3 -> 64-row slice
  const int wn = w & 1;   // 0..1 -> 64-col slice

  const f32x4 zero = {0.f, 0.f, 0.f, 0.f};
#pragma unroll
  for (int mt = 0; mt < 4; ++mt)
#pragma unroll
    for (int nt = 0; nt < 4; ++nt) acc[mt][nt] = zero;

  const int rbase = t >> 3;                      // 0..63
  const int scol = ((t & 7) ^ (rbase & 7)) * 8;  // pre-swizzled global col
  const u16* Ag = A + (size_t)(m0 + rbase) * K + scol;
  const u16* Bg = BT + (size_t)(n0 + rbase) * K + scol;
  const int sx = l15 & 7;

  // one stage = 6 global_load_lds/thread (4x A 64-row pieces, 2x B)
  auto STAGE = [&](int kt, int bufi) {
    u16* Ab = lds + bufi * BUFSZ_;
    u16* Bb = Ab + ABUF_;
    const int k0 = kt * 64;
#pragma unroll
    for (int c = 0; c < 4; ++c)
      cp16(Ag + (size_t)(c * 64) * K + k0, Ab + c * 4096 + t * 8);
#pragma unroll
    for (int c = 0; c < 2; ++c)
      cp16(Bg + (size_t)(c * 64) * K + k0, Bb + c * 4096 + t * 8);
  };

  const int NT = K / 64;  // 16
  STAGE(0, 0);
  STAGE(1, 1);

  int cur = 0;
  for (int kt = 0; kt < NT; ++kt) {
    if (kt + 2 < NT) {
      int nb = cur + 2;
      if (nb >= 3) nb -= 3;
      STAGE(kt + 2, nb);  // issue BEFORE the wait: 18 outstanding max
    }
    // readiness of buf[cur]: wait only the oldest 6 loads (counted vmcnt)
    if (kt + 2 < NT)
      asm volatile("s_waitcnt vmcnt(12)" ::: "memory");
    else if (kt + 1 < NT)
      asm volatile("s_waitcnt vmcnt(6)" ::: "memory");
    else
      asm volatile("s_waitcnt vmcnt(0)" ::: "memory");
    asm volatile("s_barrier" ::: "memory");

    const u16* Ab = lds + cur * BUFSZ_;
    const u16* Bb = Ab + ABUF_;

    // all 16 fragment reads for both kk halves, back-to-back (kk0 first)
    b16x8 af[4][2], bf2[4][2];
#pragma unroll
    for (int kk = 0; kk < 2; ++kk) {
      const int cc = ((kk * 4 + q4) ^ sx) * 8;
#pragma unroll
      for (int mt = 0; mt < 4; ++mt)
        af[mt][kk] = *(const b16x8*)(Ab + (wm * 64 + mt * 16 + l15) * 64 + cc);
#pragma unroll
      for (int nt = 0; nt < 4; ++nt)
        bf2[nt][kk] = *(const b16x8*)(Bb + (wn * 64 + nt * 16 + l15) * 64 + cc);
    }
    __builtin_amdgcn_sched_barrier(0);

    // kk0 MFMA (compiler emits counted lgkm wait for the kk0 subset)
    __builtin_amdgcn_s_setprio(1);
#pragma unroll
    for (int mt = 0; mt < 4; ++mt)
#pragma unroll
      for (int nt = 0; nt < 4; ++nt)
        acc[mt][nt] = mfma16(af[mt][0], bf2[nt][0], acc[mt][nt]);
    __builtin_amdgcn_s_setprio(0);

    // all waves' reads of buf[cur] complete before anyone can restage it
    asm volatile("s_waitcnt lgkmcnt(0)" ::: "memory");
    asm volatile("s_barrier" ::: "memory");

    __builtin_amdgcn_s_setprio(1);
#pragma unroll
    for (int mt = 0; mt < 4; ++mt)
#pragma unroll
      for (int nt = 0; nt < 4; ++nt)
        acc[mt][nt] = mfma16(af[mt][1], bf2[nt][1], acc[mt][nt]);
    __builtin_amdgcn_s_setprio(0);

    ++cur;
    if (cur == 3) cur = 0;
  }
}

// ---------------------------------------------------------------------------
// Fused QKV projection: one GEMM M=8192 x N=3072 (B = [wtq;wtk;wtv]).
// n-tile (128) always lies inside one of Q/K/V (1024 % 128 == 0).
// z=0 -> Q [B,H,S,HD], z=1 -> K [B,H,S,HD], z=2 -> V^T [B,H,HD,S]
// Grid 768 = 32by x 24bx = 3 rounds at 1 block/CU.
// L2-residency swizzle: XCD x owns by in {4x..4x+3} (A slice = 2MB, hot
// across all 3 rounds) and sweeps bx 8-per-round (B stream 2MB/round).
// ---------------------------------------------------------------------------
__global__ __launch_bounds__(512, 2) void qkv_gemm_kernel(
    const u16* __restrict__ xb, const u16* __restrict__ wt3,
    const float* __restrict__ bq, const float* __restrict__ bk,
    const float* __restrict__ bv, u16* __restrict__ Q, u16* __restrict__ Kb,
    u16* __restrict__ VT) {
  __shared__ __align__(16) u16 lds[3 * BUFSZ_];  // 144 KB
  const int wg = blockIdx.x;
  const int xcd = wg & 7;                // dispatch round-robins XCDs
  const int s = wg >> 3;                 // 0..95 slot within XCD
  const int by = xcd * 4 + (s & 3);      // 0..31: 4 A-panels pinned per XCD
  const int bx = s >> 2;                 // 0..23: B streams across rounds
  const int m0 = by * 256;
  const int n0 = bx * 128;  // fused col base 0..2944

  f32x4 acc[4][4];
  gemm256x128_mainloop(xb, wt3, D_, m0, n0, lds, acc);

  const int t = threadIdx.x;
  const int lane = t & 63, w = t >> 6;
  const int l15 = lane & 15, q4 = lane >> 4;
  const int wm = w >> 1, wn = w & 1;

  const int z = n0 >> 10;  // uniform per block
  u16* out = (z == 0) ? Q : (z == 1) ? Kb : VT;
  const float* bias = (z == 0) ? bq : (z == 1) ? bk : bv;

  for (int nt = 0; nt < 4; ++nt) {
    const int nf = n0 + wn * 64 + nt * 16 + l15;  // fused col
    const int n1 = nf & 1023;                     // col within matrix
    const float bias_v = bias[n1];
    const int h = n1 >> 6, hd = n1 & 63;
    for (int mt = 0; mt < 4; ++mt) {
      for (int r = 0; r < 4; ++r) {
        const int m = m0 + wm * 64 + mt * 16 + q4 * 4 + r;
        const int b = m >> 10, ss = m & 1023;
        const float v = acc[mt][nt][r] + bias_v;
        size_t idx;
        if (z < 2)
          idx = (((size_t)(b * H_ + h)) * S_ + ss) * HD_ + hd;
        else
          idx = (((size_t)(b * H_ + h)) * HD_ + hd) * S_ + ss;
        out[idx] = f2bf(v);
      }
    }
  }
}

// ---------------------------------------------------------------------------
// Flash attention, fixed-max softmax, transposed-score formulation.
// QBLK=128 (512 threads, 8 waves), verified round-6. Unchanged.
// ---------------------------------------------------------------------------
#define PAD_ 68   // K/V row stride (measured conflict-free)
#define QPAD_ 72  // Q/P row stride (144B = 16B-aligned for b128)
__global__ __launch_bounds__(512) void attn_kernel(
    const u16* __restrict__ Q, const u16* __restrict__ Kb,
    const u16* __restrict__ VT, const int* __restrict__ mask,
    u16* __restrict__ ctx) {
  __shared__ __align__(16) u16 QPlds[128 * QPAD_];  // Q tile, then P buffers
  __shared__ __align__(16) u16 Klds[64 * PAD_];
  __shared__ __align__(16) u16 Vlds[64 * PAD_];
  __shared__ __align__(16) float Mlds[1024];  // -14427 * mask[key]

  const int t = threadIdx.x;
  const int lane = t & 63, w = t >> 6;  // w 0..7
  const int l15 = lane & 15, q4 = lane >> 4;
  const int id = blockIdx.x;
  const int bh = id & 127;  // XCD = id%8 = bh%8 -> q-tiles of a bh co-locate
  const int b = bh >> 4, h = bh & 15;
  const int q0 = (id >> 7) * 128;  // 8 q-tiles of 128 rows

  const u16* Qbh = Q + (size_t)bh * S_ * HD_;
  const u16* Kbh = Kb + (size_t)bh * S_ * HD_;
  const u16* Vbh = VT + (size_t)bh * S_ * HD_;  // [HD][S]
  const int* maskb = mask + b * S_;

  const int srow = t >> 3, scol = (t & 7) * 8;  // srow 0..63
  {  // stage Q tile [128][64] + mask into LDS
    b16x8 q0v = *(const b16x8*)(Qbh + (size_t)(q0 + srow) * HD_ + scol);
    b16x8 q1v = *(const b16x8*)(Qbh + (size_t)(q0 + srow + 64) * HD_ + scol);
    const int2 mv = *(const int2*)(maskb + t * 2);
    *(b16x8*)(QPlds + srow * QPAD_ + scol) = q0v;
    *(b16x8*)(QPlds + (srow + 64) * QPAD_ + scol) = q1v;
    float2 mf;
    mf.x = -14427.0f * (float)mv.x;
    mf.y = -14427.0f * (float)mv.y;
    *(float2*)(Mlds + t * 2) = mf;
  }
  __syncthreads();
  // Q B-frags (lane holds Q[q=l15][d=q4*8+j]), wave-private rows
  b16x8 aq[2];
  aq[0] = *(const b16x8*)(QPlds + (w * 16 + l15) * QPAD_ + q4 * 8);
  aq[1] = *(const b16x8*)(QPlds + (w * 16 + l15) * QPAD_ + 32 + q4 * 8);

  const f32x4 zero = {0.f, 0.f, 0.f, 0.f};
  f32x4 acc[4];  // O^T tiles: acc[nt] row d=nt*16+q4*4+r, col q=l15
  for (int nt = 0; nt < 4; ++nt) acc[nt] = zero;
  float lsum = 0.f;                  // partial row-sum for q=l15
  u16* Pw = QPlds + w * 16 * QPAD_;  // wave-private P: [q(16)][key(64)]
  const float c1 = 0.18033688f;      // 0.125 * log2(e)

  // prologue: K/V registers for j=0 (one row each with 512 threads)
  b16x8 kv0 = *(const b16x8*)(Kbh + (size_t)srow * HD_ + scol);
  b16x8 vv0 = *(const b16x8*)(Vbh + (size_t)srow * S_ + scol);

  for (int j = 0; j < 16; ++j) {
    const int key0 = j * 64;
    __syncthreads();  // (A) prior iteration's K/V LDS reads complete
    *(b16x8*)(Klds + srow * PAD_ + scol) = kv0;
    *(b16x8*)(Vlds + srow * PAD_ + scol) = vv0;
    __syncthreads();  // (B) staging visible

    if (j < 15) {  // prefetch next tile's K/V during compute
      const int kn = key0 + 64;
      kv0 = *(const b16x8*)(Kbh + (size_t)(kn + srow) * HD_ + scol);
      vv0 = *(const b16x8*)(Vbh + (size_t)srow * S_ + kn + scol);
    }

    // S^T = K·Q^T: sf[nt] rows key=nt*16+q4*4+r, col q=l15
    f32x4 sf[4];
    for (int nt = 0; nt < 4; ++nt) sf[nt] = zero;
    for (int kk = 0; kk < 2; ++kk)
      for (int nt = 0; nt < 4; ++nt) {
        b16x8 bk =
            *(const b16x8*)(Klds + (nt * 16 + l15) * PAD_ + kk * 32 + q4 * 8);
        sf[nt] = mfma16(bk, aq[kk], sf[nt]);
      }

    // fixed-max softmax; mask indexed by key (row) -> broadcast float4
    for (int nt = 0; nt < 4; ++nt) {
      const float4 mk = *(const float4*)(Mlds + key0 + nt * 16 + q4 * 4);
      float p0 = __builtin_amdgcn_exp2f(sf[nt][0] * c1 + mk.x);
      float p1 = __builtin_amdgcn_exp2f(sf[nt][1] * c1 + mk.y);
      float p2 = __builtin_amdgcn_exp2f(sf[nt][2] * c1 + mk.z);
      float p3 = __builtin_amdgcn_exp2f(sf[nt][3] * c1 + mk.w);
      lsum += (p0 + p1) + (p2 + p3);
      uint2 pk;
      pk.x = ((u32)bfbits(p1) << 16) | bfbits(p0);
      pk.y = ((u32)bfbits(p3) << 16) | bfbits(p2);
      // P[q=l15][key=nt*16+q4*4 .. +3]: 4 consecutive keys, one b64 write
      *(uint2*)(Pw + l15 * QPAD_ + nt * 16 + q4 * 4) = pk;
    }
    // wave-private handoff: drain the 4 P writes only
    asm volatile("s_waitcnt lgkmcnt(0)" ::: "memory");

    // O^T += V^T·P: A=V-frag (same read as before), B=P-frag (b128 row read)
    for (int kk = 0; kk < 2; ++kk) {
      b16x8 bp = *(const b16x8*)(Pw + l15 * QPAD_ + kk * 32 + q4 * 8);
      for (int nt = 0; nt < 4; ++nt) {
        b16x8 vb =
            *(const b16x8*)(Vlds + (nt * 16 + l15) * PAD_ + kk * 32 + q4 * 8);
        acc[nt] = mfma16(vb, bp, acc[nt]);
      }
    }
  }

  // row-sum: quads hold disjoint key quarters -> reduce across quads
  lsum += __shfl_xor(lsum, 16);
  lsum += __shfl_xor(lsum, 32);
  const float inv = 1.0f / lsum;

  // epilogue: lane writes 4 consecutive d at fixed row s -> dwordx2 stores
  const int srw = q0 + w * 16 + l15;
  u16* crow = ctx + ((size_t)(b * S_ + srw)) * D_ + h * 64;
  for (int nt = 0; nt < 4; ++nt) {
    uint2 pk;
    pk.x = ((u32)bfbits(acc[nt][1] * inv) << 16) | bfbits(acc[nt][0] * inv);
    pk.y = ((u32)bfbits(acc[nt][3] * inv) << 16) | bfbits(acc[nt][2] * inv);
    *(uint2*)(crow + nt * 16 + q4 * 4) = pk;
  }
}

// ---------------------------------------------------------------------------
// Output projection + bias + residual(x f32) -> y (fp32).
// Grid 256 = 32by x 8bx = exactly 1 round at 1 block/CU. Same L2-residency
// swizzle: XCD x owns by {4x..4x+3} (A 2MB) + full wto (2MB) = 4MB.
// ---------------------------------------------------------------------------
__global__ __launch_bounds__(512, 2) void out_gemm_kernel(
    const u16* __restrict__ ctx, const u16* __restrict__ wto,
    const float* __restrict__ bo, const float* __restrict__ x,
    float* __restrict__ y) {
  __shared__ __align__(16) u16 lds[3 * BUFSZ_];  // 144 KB
  const int wg = blockIdx.x;
  const int xcd = wg & 7;
  const int s = wg >> 3;             // 0..31
  const int by = xcd * 4 + (s & 3);  // 0..31
  const int bx = s >> 2;             // 0..7
  const int m0 = by * 256, n0 = bx * 128;

  f32x4 acc[4][4];
  gemm256x128_mainloop(ctx, wto, D_, m0, n0, lds, acc);

  const int t = threadIdx.x;
  const int lane = t & 63, w = t >> 6;
  const int l15 = lane & 15, q4 = lane >> 4;
  const int wm = w >> 1, wn = w & 1;

  for (int nt = 0; nt < 4; ++nt) {
    const int n = n0 + wn * 64 + nt * 16 + l15;
    const float bias = bo[n];
    for (int mt = 0; mt < 4; ++mt) {
      for (int r = 0; r < 4; ++r) {
        const int m = m0 + wm * 64 + mt * 16 + q4 * 4 + r;
        y[(size_t)m * D_ + n] = acc[mt][nt][r] + bias + x[(size_t)m * D_ + n];
      }
    }
  }
}

// ---------------------------------------------------------------------------
// Row LayerNorm: one block per row of 1024, f32 in, f32 out
// ---------------------------------------------------------------------------
__global__ __launch_bounds__(256) void ln_kernel(const float* __restrict__ y,
                                                 const float* __restrict__ g,
                                                 const float* __restrict__ be,
                                                 float* __restrict__ out) {
  const int row = blockIdx.x, t = threadIdx.x;
  const float* yr = y + (size_t)row * D_;
  const float4 v = *(const float4*)(yr + t * 4);
  float s = v.x + v.y + v.z + v.w;
  float ss = v.x * v.x + v.y * v.y + v.z * v.z + v.w * v.w;
  for (int off = 1; off < 64; off <<= 1) {
    s += __shfl_xor(s, off);
    ss += __shfl_xor(ss, off);
  }
  __shared__ float red[8];
  const int w = t >> 6, lane = t & 63;
  if (lane == 0) {
    red[w] = s;
    red[4 + w] = ss;
  }
  __syncthreads();
  s = red[0] + red[1] + red[2] + red[3];
  ss = red[4] + red[5] + red[6] + red[7];
  const float mu = s * (1.f / 1024.f);
  const float var = ss * (1.f / 1024.f) - mu * mu;
  const float rs = rsqrtf(var + 1e-6f);
  const int c = t * 4;
  const float4 gv = *(const float4*)(g + c);
  const float4 bv = *(const float4*)(be + c);
  float4 o;
  o.x = (v.x - mu) * rs * gv.x + bv.x;
  o.y = (v.y - mu) * rs * gv.y + bv.y;
  o.z = (v.z - mu) * rs * gv.z + bv.z;
  o.w = (v.w - mu) * rs * gv.w + bv.w;
  *(float4*)(out + (size_t)row * D_ + c) = o;
}

// ---------------------------------------------------------------------------
extern "C" void kernel_launch(void* const* d_in, const int* in_sizes, int n_in,
                              void* d_out, int out_size, void* d_ws,
                              size_t ws_size, hipStream_t stream) {
  const float* x = (const float*)d_in[0];
  const int* mask = (const int*)d_in[1];
  const float* wq = (const float*)d_in[2];
  const float* bq = (const float*)d_in[3];
  const float* wk = (const float*)d_in[4];
  const float* bk = (const float*)d_in[5];
  const float* wv = (const float*)d_in[6];
  const float* bv = (const float*)d_in[7];
  const float* wo = (const float*)d_in[8];
  const float* bo = (const float*)d_in[9];
  const float* gamma = (const float*)d_in[10];
  const float* beta = (const float*)d_in[11];
  float* out = (float*)d_out;

  char* ws = (char*)d_ws;
  const size_t MB = 1024ull * 1024ull;
  u16* wtq = (u16*)(ws + 0 * MB);  // wtq/wtk/wtv contiguous = fused [3072][1024]
  u16* wtk = (u16*)(ws + 2 * MB);
  u16* wtv = (u16*)(ws + 4 * MB);
  u16* wto = (u16*)(ws + 6 * MB);
  u16* xb = (u16*)(ws + 8 * MB);    // 16MB bf16 x; dead after qkv_gemm
  u16* ctx = (u16*)(ws + 8 * MB);   // aliases xb (written by attn)
  u16* Qb = (u16*)(ws + 24 * MB);   // 16MB; dead after attn
  u16* Kb = (u16*)(ws + 40 * MB);   // 16MB; dead after attn
  u16* VTb = (u16*)(ws + 56 * MB);  // 16MB
  float* y = (float*)(ws + 24 * MB);  // 32MB fp32, aliases Qb+Kb
  // total: 72MB

  wconv_kernel<<<dim3(32, 32, 4), dim3(32, 32), 0, stream>>>(
      wq, wk, wv, wo, wtq, wtk, wtv, wto);
  xconv_kernel<<<8192, 256, 0, stream>>>(x, xb);
  qkv_gemm_kernel<<<768, 512, 0, stream>>>(xb, wtq, bq, bk, bv, Qb, Kb, VTb);
  attn_kernel<<<1024, 512, 0, stream>>>(Qb, Kb, VTb, mask, ctx);
  out_gemm_kernel<<<256, 512, 0, stream>>>(ctx, wto, bo, x, y);
  ln_kernel<<<8192, 256, 0, stream>>>(y, gamma, beta, out);
}